// Round 1
// 1110.133 us; speedup vs baseline: 1.1764x; 1.1764x over previous
//
#include <hip/hip_runtime.h>
#include <hip/hip_cooperative_groups.h>

typedef short bfv8 __attribute__((ext_vector_type(8)));  // 8 x bf16 (4 VGPRs)
typedef float fv4  __attribute__((ext_vector_type(4)));  // 4 x f32 accum
typedef unsigned long long u64;

#define T_STEPS 128
#define BATCH   64
#define FDIM    512
#define HDIM    1024
#define NCOL    4096   // 4*HDIM, gate-interleaved: n = j*4 + g (g: 0=f,1=i,2=o,3=c)
#define NCLS    513
// h ring slot: 65536 elements, BLOCK-MAJOR layout [4 grp][64 blk][16 batch][16 unit]
// (R11: was [batch][unit] row-major; block-major gives each producer block a
//  contiguous 512B = 8 full cache lines, single writer).
#define HSLOT   65536

#define PREP_N0 4194304            // convert_x  (T*B*F)
#define PREP_N1 2097152            // expand_x   (NCOL*FDIM)
#define PREP_N2 4194304            // expand_h   (NCOL*HDIM)
#define PREP_N3 4096               // bias
#define PREP_TOTAL (PREP_N0 + PREP_N1 + PREP_N2 + PREP_N3)

static __device__ __forceinline__ float b2f(unsigned short u) {
  union { unsigned int i; float f; } v; v.i = ((unsigned int)u) << 16; return v.f;
}
static __device__ __forceinline__ unsigned short f2b(float f) {
  union { float f; unsigned int i; } v; v.f = f;
  unsigned int r = v.i + 0x7FFFu + ((v.i >> 16) & 1u);   // RNE
  return (unsigned short)(r >> 16);
}
static __device__ __forceinline__ float sigm(float x) { return 1.0f / (1.0f + __expf(-x)); }
static __device__ __forceinline__ float tanh_f(float x) {
  float e = __expf(-2.0f * fabsf(x));
  float t = (1.0f - e) / (1.0f + e);
  return x >= 0.0f ? t : -t;
}

// ---- dtype detector: bf16 mode iff even-index ushorts look like bf16 N(0,1) ----
__global__ void detect_k(const unsigned short* __restrict__ xr, int* __restrict__ flag) {
  __shared__ int cnt;
  if (threadIdx.x == 0) cnt = 0;
  __syncthreads();
  int local = 0;
  for (int s = 0; s < 4; ++s) {
    int i = threadIdx.x + 256 * s;
    unsigned short u = xr[2 * i];
    int e = (u >> 7) & 0xFF;
    if (e >= 112 && e <= 131) local++;
  }
  atomicAdd(&cnt, local);
  __syncthreads();
  if (threadIdx.x == 0) *flag = (cnt >= 512) ? 1 : 0;
}

// ---- merged prep: convert x, expand WXT/WHT (tessarine big, transposed,
// gate-interleaved), bias. comp = rb ^ cb ; sign = - iff (rb odd) && (cb even).
__global__ void prep_k(const void* __restrict__ x,
                       const void* w0x, const void* w1x, const void* w2x, const void* w3x,
                       const void* w0h, const void* w1h, const void* w2h, const void* w3h,
                       const void* b0, const void* b1, const void* b2, const void* b3,
                       const int* __restrict__ flagp,
                       unsigned short* __restrict__ xbf,
                       unsigned short* __restrict__ WXT,
                       unsigned short* __restrict__ WHT,
                       float* __restrict__ biasI) {
  int fl = *flagp;
  long idx = (long)blockIdx.x * 256 + threadIdx.x;
  if (idx < PREP_N0) {
    int i = (int)idx;
    xbf[i] = fl ? ((const unsigned short*)x)[i] : f2b(((const float*)x)[i]);
    return;
  }
  idx -= PREP_N0;
  if (idx < PREP_N1) {
    int i = (int)idx;
    int n = i >> 9, k = i & 511;
    int j = n >> 2, g = n & 3;
    int rb = k >> 7, p = k & 127;               // FDIM/4 = 128
    int cb = j >> 8, q = j & 255;               // HDIM/4 = 256
    int comp = rb ^ cb;
    int neg = (rb & 1) && !(cb & 1);
    const void* W = (g == 0) ? w0x : (g == 1) ? w1x : (g == 2) ? w2x : w3x;
    int off = comp * (128 * 256) + p * 256 + q;
    unsigned short v;
    if (fl) { v = ((const unsigned short*)W)[off]; if (neg) v ^= 0x8000u; }
    else    { float f = ((const float*)W)[off]; if (neg) f = -f; v = f2b(f); }
    WXT[i] = v;
    return;
  }
  idx -= PREP_N1;
  if (idx < PREP_N2) {
    int i = (int)idx;
    int n = i >> 10, k = i & 1023;
    int j = n >> 2, g = n & 3;
    int rb = k >> 8, p = k & 255;               // HDIM/4 = 256
    int cb = j >> 8, q = j & 255;
    int comp = rb ^ cb;
    int neg = (rb & 1) && !(cb & 1);
    const void* W = (g == 0) ? w0h : (g == 1) ? w1h : (g == 2) ? w2h : w3h;
    int off = comp * (256 * 256) + p * 256 + q;
    unsigned short v;
    if (fl) { v = ((const unsigned short*)W)[off]; if (neg) v ^= 0x8000u; }
    else    { float f = ((const float*)W)[off]; if (neg) f = -f; v = f2b(f); }
    WHT[i] = v;
    return;
  }
  idx -= PREP_N2;
  {
    int i = (int)idx;                           // < 4096
    int j = i >> 2, g = i & 3;
    const void* B = (g == 0) ? b0 : (g == 1) ? b1 : (g == 2) ? b2 : b3;
    biasI[i] = fl ? b2f(((const unsigned short*)B)[j]) : ((const float*)B)[j];
  }
}

// ---- Phase B: 128-step recurrence. 4 independent batch-groups x 64 blocks.
// R11 KEY CHANGES vs R10 (attack the 8.8us/step exchange latency):
//  (1) Block-major h layout: each block writes ONE contiguous 512B region
//      (8 full 64B lines, single writer) via LDS gather + one 64-lane x 8B
//      agent store from wave 0. Kills the partial-line/RMW write
//      amplification (WRITE_SIZE 66.5MB -> ~19MB expected) and makes acks
//      cheap.
//  (2) Store-ack (s_waitcnt vmcnt(0)) moved AFTER the t+1 x-GEMM, so the
//      ~full-L3-roundtrip ack is hidden under useful MFMA work; flag fires
//      right after.
//  (3) Poll by wave 0 ONLY, with per-lane early-out masking (lanes whose
//      flag already reached t+1 stop re-loading). Cuts same-line agent-load
//      serialization at the coherence point by 4-64x. Waves 1-3 sleep at
//      s_barrier.
//  (4) No flag/poll after the last step (kernel-end release drains stores
//      for phaseC).
__global__ void __launch_bounds__(256, 1) phaseB_k(const unsigned short* __restrict__ xbf,
                                                   const unsigned short* __restrict__ WXT,
                                                   const unsigned short* __restrict__ WHT,
                                                   const float* __restrict__ biasI,
                                                   unsigned short* __restrict__ hring,
                                                   int* __restrict__ flags) {
  __shared__ unsigned short Wh[64][1032];     // 64 n-cols x 1024 k (+8 pad): 132 KB
  __shared__ float Pl[4][16][16];             // per-wave transpose staging
  __shared__ __align__(16) unsigned short Hp[16][16];  // block h gather: 16 batch x 16 units
  int tid = threadIdx.x;
  int grp = blockIdx.x >> 6;                  // 0..3 : batch group
  int blk = blockIdx.x & 63;                  // 0..63: N-col block within group
  int n0  = blk * 64;
  for (int c = tid; c < 64 * 128; c += 256) {
    int row = c >> 7, ch = c & 127;
    *(uint4*)&Wh[row][ch * 8] = *(const uint4*)&WHT[(size_t)(n0 + row) * HDIM + ch * 8];
  }
  __syncthreads();
  int w = tid >> 6, lane = tid & 63;
  int col = lane & 15, quad = lane >> 4;
  int gbatch = grp * 16 + col;                // A-frag batch row AND elementwise batch
  const unsigned short* whp = &Wh[w * 16 + col][quad * 8];
  const unsigned short* wxp = WXT + (size_t)(n0 + w * 16 + col) * FDIM + quad * 8;
  float4 bv = *(const float4*)&biasI[n0 + w * 16 + quad * 4];  // lane's unit gate biases
  int* myflag   = flags + (grp * 64 + blk) * 16;   // this block's flag (64 B stride)
  int* pollflag = flags + (grp * 64 + lane) * 16;  // lane-parallel poll target
  // Consumer fragment base (block-major slot layout). Lane (col,quad),
  // fragment f needs units [f*32+quad*8, +8) of batch gbatch:
  //   blk' = 2f + (quad>>1), u16 = (quad&1)*8  ->  element offset f*512 + fbase.
  size_t fbase = (size_t)grp * 16384 + (size_t)(quad >> 1) * 256
               + (size_t)col * 16 + (size_t)(quad & 1) * 8;
  // Producer region: this block's contiguous 256 elements (512B).
  size_t pregion = (size_t)grp * 16384 + (size_t)blk * 256;
  float creg = 0.0f;                          // c state thread-private
  // prologue: gx for t=0
  fv4 gx0 = {0.f, 0.f, 0.f, 0.f}, gx1 = {0.f, 0.f, 0.f, 0.f};
  {
    const unsigned short* xrow = xbf + (size_t)gbatch * FDIM + quad * 8;
#pragma unroll
    for (int k0 = 0; k0 < FDIM; k0 += 64) {
      bfv8 a0 = *(const bfv8*)(xrow + k0);
      bfv8 b0 = *(const bfv8*)(wxp + k0);
      bfv8 a1 = *(const bfv8*)(xrow + k0 + 32);
      bfv8 b1 = *(const bfv8*)(wxp + k0 + 32);
      gx0 = __builtin_amdgcn_mfma_f32_16x16x32_bf16(a0, b0, gx0, 0, 0, 0);
      gx1 = __builtin_amdgcn_mfma_f32_16x16x32_bf16(a1, b1, gx1, 0, 0, 0);
    }
  }
  for (int t = 0; t < T_STEPS; ++t) {
    const unsigned short* hin  = hring + (size_t)t * HSLOT;
    unsigned short*       hout = hring + (size_t)(t + 1) * HSLOT;
    // h A-fragments, plain cached 16B loads (ring slot lines are fresh ->
    // never stale; kernel-launch acquire invalidates across dispatches).
    const uint4* hq = (const uint4*)(hin + fbase);
    uint4 hs[32];
#pragma unroll
    for (int f = 0; f < 32; ++f) hs[f] = hq[f * 64];   // stride 512 elem = 1KB
    fv4 acc0 = gx0, acc1 = gx1;               // start from prefetched x-GEMM result
#pragma unroll
    for (int f = 0; f < 32; f += 2) {
      union { uint4 q; bfv8 v; } ua, ub;
      ua.q = hs[f];
      ub.q = hs[f + 1];
      bfv8 b0 = *(const bfv8*)(whp + f * 32);
      bfv8 b1 = *(const bfv8*)(whp + (f + 1) * 32);
      acc0 = __builtin_amdgcn_mfma_f32_16x16x32_bf16(ua.v, b0, acc0, 0, 0, 0);
      acc1 = __builtin_amdgcn_mfma_f32_16x16x32_bf16(ub.v, b1, acc1, 0, 0, 0);
    }
    fv4 acc = acc0 + acc1;
    // Wave-local transpose through LDS (writer wave == reader wave; no barrier).
#pragma unroll
    for (int r = 0; r < 4; ++r) Pl[w][quad * 4 + r][col] = acc[r];  // D: m=quad*4+r, n=col
    asm volatile("" ::: "memory");
    __builtin_amdgcn_s_waitcnt(0);            // ds_writes visible to own wave's ds_read
    asm volatile("" ::: "memory");
    float4 pv = *(const float4*)&Pl[w][col][quad * 4];  // (batch=col, 4 gates of unit quad)
    float fg = sigm(pv.x + bv.x);
    float ig = sigm(pv.y + bv.y);
    float og = sigm(pv.z + bv.z);
    float av = pv.w + bv.w;
    float cn = ig * tanh_f(av) + fg * creg;
    float hn = og * tanh_f(cn);
    creg = cn;
    // Gather the block's 16 batch x 16 units into LDS (batch-major, 2B each).
    Hp[col][w * 4 + quad] = f2b(hn);
    __syncthreads();                          // (A) Hp complete
    // Wave 0: single coalesced store of the whole 512B region (8 full lines),
    // agent scope so it write-throughs past the local XCD L2.
    if (w == 0) {
      u64 pk = ((const u64*)&Hp[0][0])[lane]; // batch=lane>>1, units (lane&1)*8..+4? (8B=4 units)
      __hip_atomic_store((u64*)(hout + pregion) + lane, pk,
                         __ATOMIC_RELAXED, __HIP_MEMORY_SCOPE_AGENT);
    }
    if (t + 1 < T_STEPS) {
      // x-GEMM for t+1: independent of h; hides the h-store ack latency.
      fv4 g0 = {0.f, 0.f, 0.f, 0.f}, g1 = {0.f, 0.f, 0.f, 0.f};
      const unsigned short* xrow = xbf + (size_t)((t + 1) * BATCH + gbatch) * FDIM + quad * 8;
#pragma unroll
      for (int k0 = 0; k0 < FDIM; k0 += 64) {
        bfv8 a0v = *(const bfv8*)(xrow + k0);
        bfv8 b0v = *(const bfv8*)(wxp + k0);
        bfv8 a1v = *(const bfv8*)(xrow + k0 + 32);
        bfv8 b1v = *(const bfv8*)(wxp + k0 + 32);
        g0 = __builtin_amdgcn_mfma_f32_16x16x32_bf16(a0v, b0v, g0, 0, 0, 0);
        g1 = __builtin_amdgcn_mfma_f32_16x16x32_bf16(a1v, b1v, g1, 0, 0, 0);
      }
      gx0 = g0; gx1 = g1;
      if (w == 0) {
        // Only wave 0 issued global stores this step -> only its vmcnt matters.
        asm volatile("s_waitcnt vmcnt(0)" ::: "memory");   // acks (hidden under x-GEMM)
        if (lane == 0)
          __hip_atomic_store(myflag, t + 1, __ATOMIC_RELAXED, __HIP_MEMORY_SCOPE_AGENT);
        // Poll with per-lane early-out: satisfied lanes stop re-loading (exec-
        // masked), collapsing same-line agent-load pressure at the IF$.
        u64 done = 0;
        for (;;) {
          int v = 0;
          if (!((done >> lane) & 1))
            v = __hip_atomic_load(pollflag, __ATOMIC_RELAXED, __HIP_MEMORY_SCOPE_AGENT);
          done |= __ballot(v >= t + 1);
          if (done == ~0ull) break;
          __builtin_amdgcn_s_sleep(1);
        }
      }
      __syncthreads();                        // (C) release waves 1-3
    }
  }
}

// ---- Phase C: out = h @ fco_W + fco_b  (h slot is block-major layout) ----
__global__ void phaseC_k(const unsigned short* __restrict__ h,
                         const void* __restrict__ fw, const void* __restrict__ fb,
                         const int* __restrict__ flagp, void* __restrict__ out) {
  int idx = blockIdx.x * 256 + threadIdx.x;
  if (idx >= BATCH * NCLS) return;
  int b = idx / NCLS, cc = idx - b * NCLS;
  // element(b, unit k) = grp*16384 + (k>>4)*256 + (b&15)*16 + (k&15)
  const unsigned short* hr = h + (size_t)(b >> 4) * 16384 + (size_t)(b & 15) * 16;
  float acc = 0.f;
  if (*flagp) {
    const unsigned short* fwp = (const unsigned short*)fw;
    for (int k = 0; k < HDIM; ++k)
      acc = fmaf(b2f(hr[((k >> 4) << 8) + (k & 15)]), b2f(fwp[k * NCLS + cc]), acc);
    acc += b2f(((const unsigned short*)fb)[cc]);
    ((unsigned short*)out)[idx] = f2b(acc);
  } else {
    const float* fwp = (const float*)fw;
    for (int k = 0; k < HDIM; ++k)
      acc = fmaf(b2f(hr[((k >> 4) << 8) + (k & 15)]), fwp[k * NCLS + cc], acc);
    acc += ((const float*)fb)[cc];
    ((float*)out)[idx] = acc;
  }
}

extern "C" void kernel_launch(void* const* d_in, const int* in_sizes, int n_in,
                              void* d_out, int out_size, void* d_ws, size_t ws_size,
                              hipStream_t stream) {
  const void* x   = d_in[0];
  const void* wfx = d_in[1];  const void* bfv = d_in[2];  const void* wfh = d_in[3];
  const void* wix = d_in[4];  const void* biv = d_in[5];  const void* wih = d_in[6];
  const void* wox = d_in[7];  const void* bov = d_in[8];  const void* woh = d_in[9];
  const void* wcx = d_in[10]; const void* bcv = d_in[11]; const void* wch = d_in[12];
  const void* fcw = d_in[13]; const void* fcb = d_in[14];

  char* ws = (char*)d_ws;
  int*            flag  = (int*)           (ws);                 // 256 B
  unsigned short* WXT   = (unsigned short*)(ws + 256);           // 4 MB
  unsigned short* WHT   = (unsigned short*)(ws + 4194560);       // 8 MB
  float*          biasI = (float*)         (ws + 12583168);      // 16 KB
  unsigned short* xbf   = (unsigned short*)(ws + 12599552);      // 8 MB
  unsigned short* hring = (unsigned short*)(ws + 20988160);      // 129 x 128 KB = 16.9 MB
  int*            flags = (int*)           (ws + 37896448);      // 16 KB -> total ~37.9 MB

  detect_k<<<1, 256, 0, stream>>>((const unsigned short*)x, flag);
  prep_k<<<PREP_TOTAL / 256, 256, 0, stream>>>(x, wfx, wix, wox, wcx,
                                               wfh, wih, woh, wch,
                                               bfv, biv, bov, bcv,
                                               flag, xbf, WXT, WHT, biasI);
  hipMemsetAsync(hring, 0, 131072, stream);                      // h[0] = 0
  hipMemsetAsync(flags, 0, 16384, stream);                       // barrier flags

  const unsigned short* p_x = xbf;
  const unsigned short* p_wx = WXT;
  const unsigned short* p_wh = WHT;
  const float* p_bi = biasI;
  unsigned short* p_hr = hring;
  int* p_fl = flags;
  void* kargs[] = { (void*)&p_x, (void*)&p_wx, (void*)&p_wh, (void*)&p_bi,
                    (void*)&p_hr, (void*)&p_fl };
  hipLaunchCooperativeKernel((void*)phaseB_k, dim3(256), dim3(256), kargs, 0, stream);

  // final h is ring slot 128
  phaseC_k<<<(BATCH * NCLS + 255) / 256, 256, 0, stream>>>(hring + 128 * HSLOT, fcw, fcb,
                                                           flag, d_out);
}

// Round 2
// 939.682 us; speedup vs baseline: 1.3898x; 1.1814x over previous
//
#include <hip/hip_runtime.h>
#include <hip/hip_cooperative_groups.h>

typedef short bfv8 __attribute__((ext_vector_type(8)));  // 8 x bf16 (4 VGPRs)
typedef float fv4  __attribute__((ext_vector_type(4)));  // 4 x f32 accum
typedef unsigned long long u64;

#define T_STEPS 128
#define BATCH   64
#define FDIM    512
#define HDIM    1024
#define NCOL    4096   // 4*HDIM, gate-interleaved: n = j*4 + g (g: 0=f,1=i,2=o,3=c)
#define NCLS    513
// h ring slot: 65536 elements, BLOCK-MAJOR layout [4 grp][64 blk][16 batch][16 unit]
#define HSLOT   65536

#define PREP_N0 4194304            // convert_x  (T*B*F)
#define PREP_N1 2097152            // expand_x   (NCOL*FDIM)
#define PREP_N2 4194304            // expand_h   (NCOL*HDIM)
#define PREP_N3 4096               // bias
#define PREP_TOTAL (PREP_N0 + PREP_N1 + PREP_N2 + PREP_N3)

static __device__ __forceinline__ float b2f(unsigned short u) {
  union { unsigned int i; float f; } v; v.i = ((unsigned int)u) << 16; return v.f;
}
static __device__ __forceinline__ unsigned short f2b(float f) {
  union { float f; unsigned int i; } v; v.f = f;
  unsigned int r = v.i + 0x7FFFu + ((v.i >> 16) & 1u);   // RNE
  return (unsigned short)(r >> 16);
}
static __device__ __forceinline__ float sigm(float x) { return 1.0f / (1.0f + __expf(-x)); }
static __device__ __forceinline__ float tanh_f(float x) {
  float e = __expf(-2.0f * fabsf(x));
  float t = (1.0f - e) / (1.0f + e);
  return x >= 0.0f ? t : -t;
}

// ---- dtype detector: bf16 mode iff even-index ushorts look like bf16 N(0,1) ----
__global__ void detect_k(const unsigned short* __restrict__ xr, int* __restrict__ flag) {
  __shared__ int cnt;
  if (threadIdx.x == 0) cnt = 0;
  __syncthreads();
  int local = 0;
  for (int s = 0; s < 4; ++s) {
    int i = threadIdx.x + 256 * s;
    unsigned short u = xr[2 * i];
    int e = (u >> 7) & 0xFF;
    if (e >= 112 && e <= 131) local++;
  }
  atomicAdd(&cnt, local);
  __syncthreads();
  if (threadIdx.x == 0) *flag = (cnt >= 512) ? 1 : 0;
}

// ---- merged prep: convert x, expand WXT/WHT (tessarine big, transposed,
// gate-interleaved), bias. comp = rb ^ cb ; sign = - iff (rb odd) && (cb even).
__global__ void prep_k(const void* __restrict__ x,
                       const void* w0x, const void* w1x, const void* w2x, const void* w3x,
                       const void* w0h, const void* w1h, const void* w2h, const void* w3h,
                       const void* b0, const void* b1, const void* b2, const void* b3,
                       const int* __restrict__ flagp,
                       unsigned short* __restrict__ xbf,
                       unsigned short* __restrict__ WXT,
                       unsigned short* __restrict__ WHT,
                       float* __restrict__ biasI) {
  int fl = *flagp;
  long idx = (long)blockIdx.x * 256 + threadIdx.x;
  if (idx < PREP_N0) {
    int i = (int)idx;
    xbf[i] = fl ? ((const unsigned short*)x)[i] : f2b(((const float*)x)[i]);
    return;
  }
  idx -= PREP_N0;
  if (idx < PREP_N1) {
    int i = (int)idx;
    int n = i >> 9, k = i & 511;
    int j = n >> 2, g = n & 3;
    int rb = k >> 7, p = k & 127;               // FDIM/4 = 128
    int cb = j >> 8, q = j & 255;               // HDIM/4 = 256
    int comp = rb ^ cb;
    int neg = (rb & 1) && !(cb & 1);
    const void* W = (g == 0) ? w0x : (g == 1) ? w1x : (g == 2) ? w2x : w3x;
    int off = comp * (128 * 256) + p * 256 + q;
    unsigned short v;
    if (fl) { v = ((const unsigned short*)W)[off]; if (neg) v ^= 0x8000u; }
    else    { float f = ((const float*)W)[off]; if (neg) f = -f; v = f2b(f); }
    WXT[i] = v;
    return;
  }
  idx -= PREP_N1;
  if (idx < PREP_N2) {
    int i = (int)idx;
    int n = i >> 10, k = i & 1023;
    int j = n >> 2, g = n & 3;
    int rb = k >> 8, p = k & 255;               // HDIM/4 = 256
    int cb = j >> 8, q = j & 255;
    int comp = rb ^ cb;
    int neg = (rb & 1) && !(cb & 1);
    const void* W = (g == 0) ? w0h : (g == 1) ? w1h : (g == 2) ? w2h : w3h;
    int off = comp * (256 * 256) + p * 256 + q;
    unsigned short v;
    if (fl) { v = ((const unsigned short*)W)[off]; if (neg) v ^= 0x8000u; }
    else    { float f = ((const float*)W)[off]; if (neg) f = -f; v = f2b(f); }
    WHT[i] = v;
    return;
  }
  idx -= PREP_N2;
  {
    int i = (int)idx;                           // < 4096
    int j = i >> 2, g = i & 3;
    const void* B = (g == 0) ? b0 : (g == 1) ? b1 : (g == 2) ? b2 : b3;
    biasI[i] = fl ? b2f(((const unsigned short*)B)[j]) : ((const float*)B)[j];
  }
}

// ---- Phase B: 128-step recurrence. 4 independent batch-groups x 64 blocks.
// R12 KEY CHANGES vs R11 (take everything off the flag-fire critical path):
//  (1) Flag fires at the earliest legal point: wave0 does Hp-read -> h-store
//      -> vmcnt(0) -> flag IMMEDIATELY after the Hp barrier. Wave0's x-GEMM
//      for step t is deferred to the TOP of iteration t, issued after the
//      h-loads so it executes under the h-load latency (dead time).
//  (2) (C) barrier removed: ALL 4 waves poll independently (waves 1-3 right
//      after their t+1 x-GEMM) and proceed straight to the next iteration's
//      h-loads on their own detect. Hp single-buffer stays safe WITHOUT (C):
//      wave0 reads Hp before firing its flag, and no wave can rewrite Hp
//      until it passes a poll that requires that flag -> the flag chain
//      itself orders Hp reuse.
__global__ void __launch_bounds__(256, 1) phaseB_k(const unsigned short* __restrict__ xbf,
                                                   const unsigned short* __restrict__ WXT,
                                                   const unsigned short* __restrict__ WHT,
                                                   const float* __restrict__ biasI,
                                                   unsigned short* __restrict__ hring,
                                                   int* __restrict__ flags) {
  __shared__ unsigned short Wh[64][1032];     // 64 n-cols x 1024 k (+8 pad): 132 KB
  __shared__ float Pl[4][16][16];             // per-wave transpose staging
  __shared__ __align__(16) unsigned short Hp[16][16];  // block h gather: 16 batch x 16 units
  int tid = threadIdx.x;
  int grp = blockIdx.x >> 6;                  // 0..3 : batch group
  int blk = blockIdx.x & 63;                  // 0..3 : N-col block within group
  int n0  = blk * 64;
  for (int c = tid; c < 64 * 128; c += 256) {
    int row = c >> 7, ch = c & 127;
    *(uint4*)&Wh[row][ch * 8] = *(const uint4*)&WHT[(size_t)(n0 + row) * HDIM + ch * 8];
  }
  __syncthreads();
  int w = tid >> 6, lane = tid & 63;
  int col = lane & 15, quad = lane >> 4;
  int gbatch = grp * 16 + col;                // A-frag batch row AND elementwise batch
  const unsigned short* whp = &Wh[w * 16 + col][quad * 8];
  const unsigned short* wxp = WXT + (size_t)(n0 + w * 16 + col) * FDIM + quad * 8;
  float4 bv = *(const float4*)&biasI[n0 + w * 16 + quad * 4];  // lane's unit gate biases
  int* myflag   = flags + (grp * 64 + blk) * 16;   // this block's flag (64 B stride)
  int* pollflag = flags + (grp * 64 + lane) * 16;  // lane-parallel poll target
  // Consumer fragment base (block-major slot layout). Lane (col,quad),
  // fragment f needs units [f*32+quad*8, +8) of batch gbatch:
  //   blk' = 2f + (quad>>1), u16 = (quad&1)*8  ->  element offset f*512 + fbase.
  size_t fbase = (size_t)grp * 16384 + (size_t)(quad >> 1) * 256
               + (size_t)col * 16 + (size_t)(quad & 1) * 8;
  // Producer region: this block's contiguous 256 elements (512B).
  size_t pregion = (size_t)grp * 16384 + (size_t)blk * 256;
  float creg = 0.0f;                          // c state thread-private
  // prologue: gx for t=0 (all waves)
  fv4 gx0 = {0.f, 0.f, 0.f, 0.f}, gx1 = {0.f, 0.f, 0.f, 0.f};
  {
    const unsigned short* xrow = xbf + (size_t)gbatch * FDIM + quad * 8;
#pragma unroll
    for (int k0 = 0; k0 < FDIM; k0 += 64) {
      bfv8 a0 = *(const bfv8*)(xrow + k0);
      bfv8 b0 = *(const bfv8*)(wxp + k0);
      bfv8 a1 = *(const bfv8*)(xrow + k0 + 32);
      bfv8 b1 = *(const bfv8*)(wxp + k0 + 32);
      gx0 = __builtin_amdgcn_mfma_f32_16x16x32_bf16(a0, b0, gx0, 0, 0, 0);
      gx1 = __builtin_amdgcn_mfma_f32_16x16x32_bf16(a1, b1, gx1, 0, 0, 0);
    }
  }
  for (int t = 0; t < T_STEPS; ++t) {
    const unsigned short* hin  = hring + (size_t)t * HSLOT;
    unsigned short*       hout = hring + (size_t)(t + 1) * HSLOT;
    // h A-fragments, plain cached 16B loads (ring slot lines are fresh ->
    // never stale; dispatch-boundary acquire invalidates across reps).
    const uint4* hq = (const uint4*)(hin + fbase);
    uint4 hs[32];
#pragma unroll
    for (int f = 0; f < 32; ++f) hs[f] = hq[f * 64];   // stride 512 elem = 1KB
    if (w == 0 && t > 0) {
      // Wave0's x-GEMM for CURRENT t, deferred from iteration t-1 so the
      // flag could fire early. Executes under the h-load latency above.
      fv4 g0 = {0.f, 0.f, 0.f, 0.f}, g1 = {0.f, 0.f, 0.f, 0.f};
      const unsigned short* xrow = xbf + (size_t)(t * BATCH + gbatch) * FDIM + quad * 8;
#pragma unroll
      for (int k0 = 0; k0 < FDIM; k0 += 64) {
        bfv8 a0v = *(const bfv8*)(xrow + k0);
        bfv8 b0v = *(const bfv8*)(wxp + k0);
        bfv8 a1v = *(const bfv8*)(xrow + k0 + 32);
        bfv8 b1v = *(const bfv8*)(wxp + k0 + 32);
        g0 = __builtin_amdgcn_mfma_f32_16x16x32_bf16(a0v, b0v, g0, 0, 0, 0);
        g1 = __builtin_amdgcn_mfma_f32_16x16x32_bf16(a1v, b1v, g1, 0, 0, 0);
      }
      gx0 = g0; gx1 = g1;
    }
    fv4 acc0 = gx0, acc1 = gx1;               // start from x-GEMM result
#pragma unroll
    for (int f = 0; f < 32; f += 2) {
      union { uint4 q; bfv8 v; } ua, ub;
      ua.q = hs[f];
      ub.q = hs[f + 1];
      bfv8 b0 = *(const bfv8*)(whp + f * 32);
      bfv8 b1 = *(const bfv8*)(whp + (f + 1) * 32);
      acc0 = __builtin_amdgcn_mfma_f32_16x16x32_bf16(ua.v, b0, acc0, 0, 0, 0);
      acc1 = __builtin_amdgcn_mfma_f32_16x16x32_bf16(ub.v, b1, acc1, 0, 0, 0);
    }
    fv4 acc = acc0 + acc1;
    // Wave-local transpose through LDS (writer wave == reader wave; no barrier).
#pragma unroll
    for (int r = 0; r < 4; ++r) Pl[w][quad * 4 + r][col] = acc[r];  // D: m=quad*4+r, n=col
    asm volatile("" ::: "memory");
    __builtin_amdgcn_s_waitcnt(0);            // ds_writes visible to own wave's ds_read
    asm volatile("" ::: "memory");
    float4 pv = *(const float4*)&Pl[w][col][quad * 4];  // (batch=col, 4 gates of unit quad)
    float fg = sigm(pv.x + bv.x);
    float ig = sigm(pv.y + bv.y);
    float og = sigm(pv.z + bv.z);
    float av = pv.w + bv.w;
    float cn = ig * tanh_f(av) + fg * creg;
    float hn = og * tanh_f(cn);
    creg = cn;
    // Gather the block's 16 batch x 16 units into LDS (batch-major, 2B each).
    Hp[col][w * 4 + quad] = f2b(hn);
    __syncthreads();                          // (A) Hp complete
    // Wave0: single coalesced store of the whole 512B region (8 full lines),
    // then ack + flag IMMEDIATELY (earliest legal point).
    if (w == 0) {
      u64 pk = ((const u64*)&Hp[0][0])[lane];
      __hip_atomic_store((u64*)(hout + pregion) + lane, pk,
                         __ATOMIC_RELAXED, __HIP_MEMORY_SCOPE_AGENT);
    }
    if (t + 1 < T_STEPS) {
      if (w == 0) {
        asm volatile("s_waitcnt vmcnt(0)" ::: "memory");   // h stores at IF$
        if (lane == 0)
          __hip_atomic_store(myflag, t + 1, __ATOMIC_RELAXED, __HIP_MEMORY_SCOPE_AGENT);
      } else {
        // Waves 1-3: x-GEMM for t+1 overlaps the flag-propagation window.
        fv4 g0 = {0.f, 0.f, 0.f, 0.f}, g1 = {0.f, 0.f, 0.f, 0.f};
        const unsigned short* xrow = xbf + (size_t)((t + 1) * BATCH + gbatch) * FDIM + quad * 8;
#pragma unroll
        for (int k0 = 0; k0 < FDIM; k0 += 64) {
          bfv8 a0v = *(const bfv8*)(xrow + k0);
          bfv8 b0v = *(const bfv8*)(wxp + k0);
          bfv8 a1v = *(const bfv8*)(xrow + k0 + 32);
          bfv8 b1v = *(const bfv8*)(wxp + k0 + 32);
          g0 = __builtin_amdgcn_mfma_f32_16x16x32_bf16(a0v, b0v, g0, 0, 0, 0);
          g1 = __builtin_amdgcn_mfma_f32_16x16x32_bf16(a1v, b1v, g1, 0, 0, 0);
        }
        gx0 = g0; gx1 = g1;
      }
      asm volatile("" ::: "memory");
      // ALL waves poll independently (per-lane early-out); no release barrier.
      // Each wave proceeds to its next-iteration h-loads on its own detect.
      u64 done = 0;
      for (;;) {
        int v = 0;
        if (!((done >> lane) & 1))
          v = __hip_atomic_load(pollflag, __ATOMIC_RELAXED, __HIP_MEMORY_SCOPE_AGENT);
        done |= __ballot(v >= t + 1);
        if (done == ~0ull) break;
        __builtin_amdgcn_s_sleep(1);
      }
      asm volatile("" ::: "memory");
    }
  }
}

// ---- Phase C: out = h @ fco_W + fco_b  (h slot is block-major layout) ----
__global__ void phaseC_k(const unsigned short* __restrict__ h,
                         const void* __restrict__ fw, const void* __restrict__ fb,
                         const int* __restrict__ flagp, void* __restrict__ out) {
  int idx = blockIdx.x * 256 + threadIdx.x;
  if (idx >= BATCH * NCLS) return;
  int b = idx / NCLS, cc = idx - b * NCLS;
  // element(b, unit k) = grp*16384 + (k>>4)*256 + (b&15)*16 + (k&15)
  const unsigned short* hr = h + (size_t)(b >> 4) * 16384 + (size_t)(b & 15) * 16;
  float acc = 0.f;
  if (*flagp) {
    const unsigned short* fwp = (const unsigned short*)fw;
    for (int k = 0; k < HDIM; ++k)
      acc = fmaf(b2f(hr[((k >> 4) << 8) + (k & 15)]), b2f(fwp[k * NCLS + cc]), acc);
    acc += b2f(((const unsigned short*)fb)[cc]);
    ((unsigned short*)out)[idx] = f2b(acc);
  } else {
    const float* fwp = (const float*)fw;
    for (int k = 0; k < HDIM; ++k)
      acc = fmaf(b2f(hr[((k >> 4) << 8) + (k & 15)]), fwp[k * NCLS + cc], acc);
    acc += ((const float*)fb)[cc];
    ((float*)out)[idx] = acc;
  }
}

extern "C" void kernel_launch(void* const* d_in, const int* in_sizes, int n_in,
                              void* d_out, int out_size, void* d_ws, size_t ws_size,
                              hipStream_t stream) {
  const void* x   = d_in[0];
  const void* wfx = d_in[1];  const void* bfv = d_in[2];  const void* wfh = d_in[3];
  const void* wix = d_in[4];  const void* biv = d_in[5];  const void* wih = d_in[6];
  const void* wox = d_in[7];  const void* bov = d_in[8];  const void* woh = d_in[9];
  const void* wcx = d_in[10]; const void* bcv = d_in[11]; const void* wch = d_in[12];
  const void* fcw = d_in[13]; const void* fcb = d_in[14];

  char* ws = (char*)d_ws;
  int*            flag  = (int*)           (ws);                 // 256 B
  unsigned short* WXT   = (unsigned short*)(ws + 256);           // 4 MB
  unsigned short* WHT   = (unsigned short*)(ws + 4194560);       // 8 MB
  float*          biasI = (float*)         (ws + 12583168);      // 16 KB
  unsigned short* xbf   = (unsigned short*)(ws + 12599552);      // 8 MB
  unsigned short* hring = (unsigned short*)(ws + 20988160);      // 129 x 128 KB = 16.9 MB
  int*            flags = (int*)           (ws + 37896448);      // 16 KB -> total ~37.9 MB

  detect_k<<<1, 256, 0, stream>>>((const unsigned short*)x, flag);
  prep_k<<<PREP_TOTAL / 256, 256, 0, stream>>>(x, wfx, wix, wox, wcx,
                                               wfh, wih, woh, wch,
                                               bfv, biv, bov, bcv,
                                               flag, xbf, WXT, WHT, biasI);
  hipMemsetAsync(hring, 0, 131072, stream);                      // h[0] = 0
  hipMemsetAsync(flags, 0, 16384, stream);                       // barrier flags

  const unsigned short* p_x = xbf;
  const unsigned short* p_wx = WXT;
  const unsigned short* p_wh = WHT;
  const float* p_bi = biasI;
  unsigned short* p_hr = hring;
  int* p_fl = flags;
  void* kargs[] = { (void*)&p_x, (void*)&p_wx, (void*)&p_wh, (void*)&p_bi,
                    (void*)&p_hr, (void*)&p_fl };
  hipLaunchCooperativeKernel((void*)phaseB_k, dim3(256), dim3(256), kargs, 0, stream);

  // final h is ring slot 128
  phaseC_k<<<(BATCH * NCLS + 255) / 256, 256, 0, stream>>>(hring + 128 * HSLOT, fcw, fcb,
                                                           flag, d_out);
}